// Round 11
// baseline (432.127 us; speedup 1.0000x reference)
//
#include <hip/hip_runtime.h>

// MixSelfAttention (B=2, L=1024, H=8, E=64), float32. ONE fused kernel with a
// MANUAL grid barrier (cooperative launch failed under graph capture in r10 —
// output stayed zeroed). 512 blocks x 256 thr; __launch_bounds__(256,2) + LDS
// 29KB guarantee 2 blocks/CU co-residency so the spin barrier cannot deadlock.
// Barrier: monotonic counter (memset to 0 each launch via hipMemsetAsync node),
// block tid0 atomic-arrives then spins for 512*phase, threadfence on both sides.
//   A: kw tile-transpose W->Wt + 2x k1 circular-corr units/blk -> acp
//   B: d2a amp/ampTF reductions (512 logical = exact)
//   C: d2b top-35 (blocks 0..31) -> St/Stf
//   D: d3 k4 scores+softmax -> P | kb WVp partials (1664 logical, looped)
//   E: k6 output (512 logical: bh x 32-l chunks)

#define NTOP 35
#define NJ 70
#define LLMIN (-0x7FFFFFFFFFFFFFFFLL - 1)

static __device__ __forceinline__ void fma4(float4& a, float4 q, float4 k) {
  a.x = fmaf(q.x,k.x,a.x); a.y = fmaf(q.y,k.y,a.y);
  a.z = fmaf(q.z,k.z,a.z); a.w = fmaf(q.w,k.w,a.w);
}

// manual grid barrier: monotonic counter, target = 512*phase
static __device__ __forceinline__ void gbar(unsigned* cnt, unsigned target) {
  __syncthreads();
  if (threadIdx.x == 0) {
    __threadfence();                              // release prior writes
    __hip_atomic_fetch_add(cnt, 1u, __ATOMIC_ACQ_REL, __HIP_MEMORY_SCOPE_AGENT);
    while (__hip_atomic_load(cnt, __ATOMIC_ACQUIRE, __HIP_MEMORY_SCOPE_AGENT)
           < target) {
      __builtin_amdgcn_s_sleep(8);
    }
    __threadfence();                              // acquire others' writes
  }
  __syncthreads();
}

// single-wave top-35 (lanes 0..63), vals[1024] ready, jax tie-break
static __device__ __forceinline__ void wave_top35(const float* vals, int* out) {
  int lane = threadIdx.x & 63;
  long long kreg[16];
  long long lmax = LLMIN;
  #pragma unroll
  for (int s = 0; s < 16; ++s) {
    int l = (s << 6) + lane;
    long long key = ((long long)(int)__float_as_uint(vals[l]) << 32)
                    | (unsigned int)(1023 - l);
    kreg[s] = key;
    lmax = key > lmax ? key : lmax;
  }
  for (int it = 0; it < NTOP; ++it) {
    long long g = lmax;
    #pragma unroll
    for (int off = 1; off < 64; off <<= 1) {
      long long o = __shfl_xor(g, off);
      g = o > g ? o : g;
    }
    if (lane == 0) out[it] = 1023 - (int)(g & 0xFFFFFFFFLL);
    if (lmax == g) {
      lmax = LLMIN;
      #pragma unroll
      for (int s = 0; s < 16; ++s) {
        if (kreg[s] == g) kreg[s] = LLMIN;
        lmax = kreg[s] > lmax ? kreg[s] : lmax;
      }
    }
  }
}

// XOR16 swizzle: conflict-free for stride-1 staging AND window reads
static __device__ __forceinline__ int qsw(int r) { return r ^ ((r >> 4) & 7); }

__global__ __launch_bounds__(256, 2) void fused(
    const float* __restrict__ q, const float* __restrict__ k,
    const float* __restrict__ tfq, const float* __restrict__ w,
    const float* __restrict__ bias, const float* __restrict__ values,
    float* __restrict__ out,
    float* __restrict__ acp, float* __restrict__ Wt,
    float* __restrict__ P, float* __restrict__ WVp,
    float* __restrict__ amp, float* __restrict__ ampTF,
    int* __restrict__ St, int* __restrict__ Stf,
    unsigned* __restrict__ cnt) {
  __shared__ float smem[7272];          // 29088 B (max phase: E = 7200 floats)
  int bid = blockIdx.x;                 // 0..511
  int tid = threadIdx.x;

  // ================= Phase A: kw + 2x k1 =================
  {
    // ---- kw: 64x64 tile transpose, 65-pad ----
    int c0 = (bid & 31) << 6, r0 = (bid >> 5) << 6;
    float* tile = smem;                 // 64*65 = 4160 floats
    #pragma unroll
    for (int s = 0; s < 4; ++s) {
      int idx = (s << 8) + tid;
      int r = idx >> 4, c4 = idx & 15;
      float4 vv = *reinterpret_cast<const float4*>(
          w + (size_t)(r0 + r)*2048 + c0 + (c4 << 2));
      float* tp = tile + r*65 + (c4 << 2);
      tp[0] = vv.x; tp[1] = vv.y; tp[2] = vv.z; tp[3] = vv.w;
    }
    __syncthreads();
    #pragma unroll
    for (int s = 0; s < 4; ++s) {
      int idx = (s << 8) + tid;
      int c = idx >> 4, r4 = idx & 15;
      float4 ov;
      ov.x = tile[(r4*4 + 0)*65 + c];
      ov.y = tile[(r4*4 + 1)*65 + c];
      ov.z = tile[(r4*4 + 2)*65 + c];
      ov.w = tile[(r4*4 + 3)*65 + c];
      *reinterpret_cast<float4*>(Wt + (size_t)(c0 + c)*1024 + r0 + (r4 << 2)) = ov;
    }
    // ---- k1 twice ----
    float4* QP = reinterpret_cast<float4*>(smem);        // 1024 f4
    float4* Ks = QP + 1024;                              // 256 f4
    for (int u = 0; u < 2; ++u) {
      int kid = bid + (u << 9);         // 0..1023
      int bh = kid & 15;  int eg = (kid >> 4) & 15;  int tc = kid >> 8;
      int b = bh >> 3, h = bh & 7;
      const float* qb  = q + (size_t)b*524288 + h*64 + eg*4;
      const float* kbp = k + (size_t)b*524288 + h*64 + eg*4;
      __syncthreads();                  // prior LDS readers done
      for (int r = tid; r < 1024; r += 256)
        QP[qsw(r)] = *reinterpret_cast<const float4*>(qb + (size_t)r*512);
      Ks[tid] = *reinterpret_cast<const float4*>(kbp + (size_t)((tc << 8) + tid)*512);
      __syncthreads();
      int tau0 = tid << 2;
      int tt0 = tc << 8;
      float4 acc[4];
      #pragma unroll
      for (int i = 0; i < 4; ++i) acc[i] = make_float4(0,0,0,0);
      int wb = tt0 + tau0;
      float4 A0 = QP[qsw((wb    ) & 1023)], A1 = QP[qsw((wb + 1) & 1023)];
      float4 A2 = QP[qsw((wb + 2) & 1023)], A3 = QP[qsw((wb + 3) & 1023)];
      float4 B0 = QP[qsw((wb + 4) & 1023)], B1 = QP[qsw((wb + 5) & 1023)];
      float4 B2 = QP[qsw((wb + 6) & 1023)], B3 = QP[qsw((wb + 7) & 1023)];
      for (int t = 0; t < 256; t += 8) {
        int S = wb + t + 8;
        float4 kv;
        kv = Ks[t+0];
        fma4(acc[0],A0,kv); fma4(acc[1],A1,kv); fma4(acc[2],A2,kv); fma4(acc[3],A3,kv);
        A0 = QP[qsw((S+0) & 1023)];
        kv = Ks[t+1];
        fma4(acc[0],A1,kv); fma4(acc[1],A2,kv); fma4(acc[2],A3,kv); fma4(acc[3],B0,kv);
        A1 = QP[qsw((S+1) & 1023)];
        kv = Ks[t+2];
        fma4(acc[0],A2,kv); fma4(acc[1],A3,kv); fma4(acc[2],B0,kv); fma4(acc[3],B1,kv);
        A2 = QP[qsw((S+2) & 1023)];
        kv = Ks[t+3];
        fma4(acc[0],A3,kv); fma4(acc[1],B0,kv); fma4(acc[2],B1,kv); fma4(acc[3],B2,kv);
        A3 = QP[qsw((S+3) & 1023)];
        kv = Ks[t+4];
        fma4(acc[0],B0,kv); fma4(acc[1],B1,kv); fma4(acc[2],B2,kv); fma4(acc[3],B3,kv);
        B0 = QP[qsw((S+4) & 1023)];
        kv = Ks[t+5];
        fma4(acc[0],B1,kv); fma4(acc[1],B2,kv); fma4(acc[2],B3,kv); fma4(acc[3],A0,kv);
        B1 = QP[qsw((S+5) & 1023)];
        kv = Ks[t+6];
        fma4(acc[0],B2,kv); fma4(acc[1],B3,kv); fma4(acc[2],A0,kv); fma4(acc[3],A1,kv);
        B2 = QP[qsw((S+6) & 1023)];
        kv = Ks[t+7];
        fma4(acc[0],B3,kv); fma4(acc[1],A0,kv); fma4(acc[2],A1,kv); fma4(acc[3],A2,kv);
        B3 = QP[qsw((S+7) & 1023)];
      }
      float4* op = reinterpret_cast<float4*>(acp)
                 + (((size_t)((bh*16 + eg)*4 + tc)) << 10) + tau0;
      #pragma unroll
      for (int i = 0; i < 4; ++i) op[i] = acc[i];
    }
  }
  gbar(cnt, 512);

  // ================= Phase B: d2a (512 logical = exact) =================
  {
    float* red = smem;                  // 256 floats
    int lane = tid & 63, g = tid >> 6;
    if (bid < 256) {                    // t: tc-combine + square + e-sum
      int bh = bid >> 4, tg = bid & 15;
      int tau = (tg << 6) + lane;
      const float4* A = reinterpret_cast<const float4*>(acp);
      float s = 0.f;
      #pragma unroll
      for (int eg4 = 0; eg4 < 4; ++eg4) {
        int eg = (g << 2) + eg4;
        const float4* E = A + (((size_t)(bh*16 + eg)) << 12);
        float4 c0 = E[tau], c1 = E[1024+tau], c2 = E[2048+tau], c3 = E[3072+tau];
        float x = c0.x+c1.x+c2.x+c3.x;
        float y = c0.y+c1.y+c2.y+c3.y;
        float z = c0.z+c1.z+c2.z+c3.z;
        float w2 = c0.w+c1.w+c2.w+c3.w;
        s += x*x + y*y + z*z + w2*w2;
      }
      red[tid] = s;
      __syncthreads();
      if (g == 0)
        amp[bh*1024 + tau] = red[lane] + red[64+lane] + red[128+lane] + red[192+lane];
    } else {                            // tf: row norms
      int wid = bid - 256;
      int bh = wid >> 4, lg = wid & 15;
      int b = bh >> 3, h = bh & 7;
      int l = (lg << 6) + lane;
      const float4* p = reinterpret_cast<const float4*>(
          tfq + (((size_t)(b*1024 + l)*8 + h) << 6)) + (g << 2);
      float s = 0.f;
      #pragma unroll
      for (int i = 0; i < 4; ++i) {
        float4 vv = p[i];
        s += vv.x*vv.x + vv.y*vv.y + vv.z*vv.z + vv.w*vv.w;
      }
      red[tid] = s;
      __syncthreads();
      if (g == 0)
        ampTF[bh*1024 + l] = red[lane] + red[64+lane] + red[128+lane] + red[192+lane];
    }
  }
  gbar(cnt, 1024);

  // ================= Phase C: d2b top-35 (blocks 0..31) =================
  if (bid < 32) {
    bool isT = bid < 16;
    int bh = isT ? bid : bid - 16;
    const float* src = (isT ? amp : ampTF) + bh*1024;
    float* vals = smem;                 // 1024 floats
    for (int i = tid; i < 1024; i += 256) vals[i] = src[i];
    __syncthreads();
    if (tid < 64) wave_top35(vals, (isT ? St : Stf) + bh*40);
  }
  gbar(cnt, 1536);

  // ================= Phase D: d3 (1664 logical, looped) =================
  for (int lb = bid; lb < 1664; lb += 512) {
    __syncthreads();                    // prior iteration's LDS readers done
    float* f = smem;
    float4* smbuf = reinterpret_cast<float4*>(smem);
    if (lb >= 512) {                    // ---- kb ----
      int kbid = lb - 512;
      int jq = kbid / 64;
      int rem = kbid - jq*64;
      int bh = rem >> 2, mc = rem & 3;
      int b = bh >> 3, h = bh & 7;
      int j0 = jq << 2;
      int mbase = mc << 8;
      float* rows = f + 1024;
      #pragma unroll
      for (int x = 0; x < 4; ++x) {
        int j = j0 + x;
        const float* pj;
        if (j < NTOP)      pj = Wt + (size_t)St [bh*40 + j]*1024;
        else if (j < NJ)   pj = Wt + (size_t)(1024 + Stf[bh*40 + j-NTOP])*1024;
        else if (j == NJ)  pj = bias;
        else               pj = Wt;     // j==71: garbage, zeroed in epilogue
        rows[(x << 8) + tid] = pj[mbase + tid];
      }
      __syncthreads();
      int d = tid & 63, mp = tid >> 6;
      float a0=0.f, a1=0.f, a2=0.f, a3=0.f;
      const float4* r4 = reinterpret_cast<const float4*>(rows);
      const float* vbase = values
          + (((size_t)(b*1024 + mbase + (mp << 6))*8 + h) << 6) + d;
      #pragma unroll 4
      for (int i4 = 0; i4 < 16; ++i4) {
        float4 w0 = r4[       (mp << 4) + i4];
        float4 w1 = r4[ 64  + (mp << 4) + i4];
        float4 w2 = r4[128  + (mp << 4) + i4];
        float4 w3 = r4[192  + (mp << 4) + i4];
        float v0 = vbase[(size_t)((i4 << 2) + 0)*512];
        float v1 = vbase[(size_t)((i4 << 2) + 1)*512];
        float v2 = vbase[(size_t)((i4 << 2) + 2)*512];
        float v3 = vbase[(size_t)((i4 << 2) + 3)*512];
        a0 = fmaf(w0.x,v0,a0); a0 = fmaf(w0.y,v1,a0);
        a0 = fmaf(w0.z,v2,a0); a0 = fmaf(w0.w,v3,a0);
        a1 = fmaf(w1.x,v0,a1); a1 = fmaf(w1.y,v1,a1);
        a1 = fmaf(w1.z,v2,a1); a1 = fmaf(w1.w,v3,a1);
        a2 = fmaf(w2.x,v0,a2); a2 = fmaf(w2.y,v1,a2);
        a2 = fmaf(w2.z,v2,a2); a2 = fmaf(w2.w,v3,a2);
        a3 = fmaf(w3.x,v0,a3); a3 = fmaf(w3.y,v1,a3);
        a3 = fmaf(w3.z,v2,a3); a3 = fmaf(w3.w,v3,a3);
      }
      float4* red = smbuf;
      red[tid] = make_float4(a0, a1, a2, a3);
      __syncthreads();
      int jj = tid >> 6, dd = tid & 63;
      float4 r0 = red[dd], r1 = red[64+dd], r2 = red[128+dd], r3 = red[192+dd];
      float s;
      if (jj == 0)      s = r0.x + r1.x + r2.x + r3.x;
      else if (jj == 1) s = r0.y + r1.y + r2.y + r3.y;
      else if (jj == 2) s = r0.z + r1.z + r2.z + r3.z;
      else              s = r0.w + r1.w + r2.w + r3.w;
      if (j0 + jj > NJ) s = 0.f;
      WVp[(size_t)mc*73728 + ((size_t)bh*72 + j0 + jj)*64 + dd] = s;
    } else {                            // ---- k4 ----
      int bh = lb >> 5;  int m0 = (lb & 31) << 5;
      int b = bh >> 3, h = bh & 7;
      float* qs   = f;
      float* ts   = f + 2240;
      float* sc   = f + 4480;
      float* invs = f + 6816;
      for (int i = tid; i < NTOP*64; i += 256) {
        int j = i >> 6, e = i & 63;
        qs[i] = q  [(((size_t)(b*1024 + St [bh*40 + j])*8 + h) << 6) + e];
        ts[i] = tfq[(((size_t)(b*1024 + Stf[bh*40 + j])*8 + h) << 6) + e];
      }
      __syncthreads();
      int mi = tid & 31, g = tid >> 5;
      int br = g >> 2, g4 = g & 3;
      int m = m0 + mi;
      const float* src = br ? tfq : k;
      float4 kr[16];
      const float4* p = reinterpret_cast<const float4*>(
          src + (((size_t)(b*1024 + m)*8 + h) << 6));
      #pragma unroll
      for (int i = 0; i < 16; ++i) kr[i] = p[i];
      const float4* fs4 = reinterpret_cast<const float4*>(br ? ts : qs);
      int sb = br ? NTOP : 0;
      for (int j = g4; j < NTOP; j += 4) {
        float s = 0.f;
        #pragma unroll
        for (int e4 = 0; e4 < 16; ++e4) {
          float4 qv = fs4[j*16 + e4];
          s += qv.x*kr[e4].x + qv.y*kr[e4].y + qv.z*kr[e4].z + qv.w*kr[e4].w;
        }
        sc[mi*73 + sb + j] = s * 0.125f;
      }
      __syncthreads();
      if (tid < 32) {
        float mx = -1e30f;
        for (int j = 0; j < NJ; ++j) mx = fmaxf(mx, sc[tid*73 + j]);
        float sum = 0.f;
        for (int j = 0; j < NJ; ++j) {
          float e = __expf(sc[tid*73 + j] - mx);
          sc[tid*73 + j] = e; sum += e;
        }
        invs[tid] = 1.0f / sum;
      }
      __syncthreads();
      float* Pb = P + ((size_t)bh*1024 + m0)*72;
      for (int i = tid; i < 32*72; i += 256) {
        int mm = i / 72, j = i - mm*72;
        Pb[i] = (j < NJ) ? sc[mm*73 + j] * invs[mm] : 0.f;
      }
    }
  }
  gbar(cnt, 2048);

  // ================= Phase E: k6 (512 logical: bh x 32-l chunks) =============
  {
    int bh = bid >> 5, lc2 = bid & 31;
    int l0 = lc2 << 5;                  // 32 l's per block
    int b = bh >> 3, h = bh & 7;
    float* wv = smem;                   // 72*64 = 4608
    float* Pl = smem + 4608;            // stride 36 (f4-aligned)
    {
      const float* W0 = WVp + (size_t)bh*4608;
      for (int i = tid; i < 4608; i += 256)
        wv[i] = W0[i] + W0[73728 + i] + W0[147456 + i] + W0[221184 + i];
    }
    {
      const float* Pg = P + ((size_t)bh*1024 + l0)*72;
      for (int i = tid; i < 32*72; i += 256) {
        int l = i / 72, j = i - l*72;
        Pl[j*36 + l] = Pg[i];
      }
    }
    __syncthreads();
    int d = tid & 63, lg = tid >> 6;    // 4 l-groups of 8
    int lb2 = lg << 3;
    float acc[8];
    float base = wv[NJ*64 + d];
    #pragma unroll
    for (int i = 0; i < 8; ++i) acc[i] = base;
    for (int j = 0; j < NJ; ++j) {
      float wvj = wv[j*64 + d];
      const float4* pr = reinterpret_cast<const float4*>(Pl + j*36 + lb2);
      float4 p0 = pr[0], p1 = pr[1];
      acc[0] = fmaf(p0.x, wvj, acc[0]); acc[1] = fmaf(p0.y, wvj, acc[1]);
      acc[2] = fmaf(p0.z, wvj, acc[2]); acc[3] = fmaf(p0.w, wvj, acc[3]);
      acc[4] = fmaf(p1.x, wvj, acc[4]); acc[5] = fmaf(p1.y, wvj, acc[5]);
      acc[6] = fmaf(p1.z, wvj, acc[6]); acc[7] = fmaf(p1.w, wvj, acc[7]);
    }
    #pragma unroll
    for (int i = 0; i < 8; ++i) {
      int l = l0 + lb2 + i;
      out[(((size_t)(b*1024 + l)*8 + h) << 6) + d] = acc[i];
    }
  }
}

extern "C" void kernel_launch(void* const* d_in, const int* in_sizes, int n_in,
                              void* d_out, int out_size, void* d_ws, size_t ws_size,
                              hipStream_t stream) {
  const float* tfq  = (const float*)d_in[0];
  const float* q    = (const float*)d_in[1];
  const float* k    = (const float*)d_in[2];
  const float* v    = (const float*)d_in[3];
  const float* tw   = (const float*)d_in[5];
  const float* tb   = (const float*)d_in[6];
  float* out = (float*)d_out;

  char* ws = (char*)d_ws;
  float* acp  = (float*)(ws);                       // 16,777,216
  float* Wt   = (float*)(ws + 16785408);            // 8,388,608
  float* P    = (float*)(ws + 25174016);            // 4,718,592
  float* WVp  = (float*)(ws + 29892608);            // 1,179,648
  float* amp  = (float*)(ws + 31072256);            // 64 KB
  float* ampTF= (float*)(ws + 31137792);            // 64 KB
  int*   St   = (int*)  (ws + 31203328);            // 8 KB
  int*   Stf  = (int*)  (ws + 31211520);            // 8 KB
  unsigned* cnt = (unsigned*)(ws + 31219712);       // 64 B barrier counter

  hipMemsetAsync(cnt, 0, 64, stream);
  fused<<<512, 256, 0, stream>>>(q, k, tfq, tw, tb, v, out,
                                 acp, Wt, P, WVp, amp, ampTF, St, Stf, cnt);
}

// Round 12
// 185.571 us; speedup vs baseline: 2.3286x; 2.3286x over previous
//
#include <hip/hip_runtime.h>

// MixSelfAttention (B=2, L=1024, H=8, E=64), float32 in/out. 5 dispatches
// (fusion reverted: coop launch fails under graph capture, manual barrier
// costs ~75us each). d1 fix: k1 was LDS-PIPE-bound (2048 ds_read_b128/block
// x 12cyc x 4 blocks/CU = 41us, matching measured 44): half the reads were
// wave-uniform Ks broadcasts. Now Ks lives in per-lane regs (Kr0..3, loaded
// once) and each step's k-vector comes via v_readlane (VALU pipe, uniform
// lane idx) -> LDS reads/block ~halved.
//   D1 d1: kw tile-transpose W -> Wt (blocks 0..511, 65-pad) | k1 corr
//          partials (512..1535), T=4 taus/thread, depth-5 window pipeline,
//          reg-Ks + readlane -> acp[bh][eg][tc][tau][4e]
//   D2a: 512 blocks; t: tc-combine+square+e-sum -> amp; tf: row norms -> ampTF
//   D2b: 32 blocks x 64 thr; single-wave top-35 -> St / Stf
//   D3 d3: k4 scores+softmax -> P (0..511) | kb WVp partials (512..1663)
//   D4 k6: per-bh blocks, 512 thr; Wv=sum_mc WVp in LDS + transposed P

#define NTOP 35
#define NJ 70
#define LLMIN (-0x7FFFFFFFFFFFFFFFLL - 1)

static __device__ __forceinline__ void fma4(float4& a, float4 q, float4 k) {
  a.x = fmaf(q.x,k.x,a.x); a.y = fmaf(q.y,k.y,a.y);
  a.z = fmaf(q.z,k.z,a.z); a.w = fmaf(q.w,k.w,a.w);
}

// broadcast one lane's float / float4 to all lanes (VALU pipe, not LDS)
static __device__ __forceinline__ float rdl(float v, int l) {
  return __uint_as_float((unsigned)__builtin_amdgcn_readlane(
      (int)__float_as_uint(v), l));
}
static __device__ __forceinline__ float4 rdl4(float4 v, int l) {
  return make_float4(rdl(v.x,l), rdl(v.y,l), rdl(v.z,l), rdl(v.w,l));
}

// single-wave top-35 (64-thread block), vals[1024] ready, jax tie-break
static __device__ __forceinline__ void wave_top35(const float* vals, int* out) {
  int lane = threadIdx.x;
  long long kreg[16];
  long long lmax = LLMIN;
  #pragma unroll
  for (int s = 0; s < 16; ++s) {
    int l = (s << 6) + lane;
    long long key = ((long long)(int)__float_as_uint(vals[l]) << 32)
                    | (unsigned int)(1023 - l);
    kreg[s] = key;
    lmax = key > lmax ? key : lmax;
  }
  for (int it = 0; it < NTOP; ++it) {
    long long g = lmax;
    #pragma unroll
    for (int off = 1; off < 64; off <<= 1) {
      long long o = __shfl_xor(g, off);
      g = o > g ? o : g;
    }
    if (lane == 0) out[it] = 1023 - (int)(g & 0xFFFFFFFFLL);
    if (lmax == g) {
      lmax = LLMIN;
      #pragma unroll
      for (int s = 0; s < 16; ++s) {
        if (kreg[s] == g) kreg[s] = LLMIN;
        lmax = kreg[s] > lmax ? kreg[s] : lmax;
      }
    }
  }
}

// XOR16 swizzle: conflict-free for stride-1 staging AND window reads
static __device__ __forceinline__ int qsw(int r) { return r ^ ((r >> 4) & 7); }

// ---------------- D1: kw (blocks 0..511) | k1 (512..1535), 256 thr ----------------
__global__ __launch_bounds__(256) void d1_prep(
    const float* __restrict__ q, const float* __restrict__ k,
    const float* __restrict__ w,
    float* __restrict__ Wt, float* __restrict__ acp) {
  __shared__ float smem[5200];          // 20.8 KB: QP 1024 f4 + Ks 256 f4 / kw tile
  int bid = blockIdx.x;
  int tid = threadIdx.x;
  if (bid < 512) {                      // ---- kw: f4-load 65-pad transpose ----
    int c0 = (bid & 31) << 6, r0 = (bid >> 5) << 6;
    float* tile = smem;                 // 64 x 65 floats = 4160 < 5200
    #pragma unroll
    for (int s = 0; s < 4; ++s) {
      int idx = (s << 8) + tid;         // 0..1023 f4 elems
      int r = idx >> 4, c4 = idx & 15;
      float4 vv = *reinterpret_cast<const float4*>(
          w + (size_t)(r0 + r)*2048 + c0 + (c4 << 2));
      float* tp = tile + r*65 + (c4 << 2);
      tp[0] = vv.x; tp[1] = vv.y; tp[2] = vv.z; tp[3] = vv.w;
    }
    __syncthreads();
    #pragma unroll
    for (int s = 0; s < 4; ++s) {
      int idx = (s << 8) + tid;
      int c = idx >> 4, r4 = idx & 15;
      float4 ov;
      ov.x = tile[(r4*4 + 0)*65 + c];
      ov.y = tile[(r4*4 + 1)*65 + c];
      ov.z = tile[(r4*4 + 2)*65 + c];
      ov.w = tile[(r4*4 + 3)*65 + c];
      *reinterpret_cast<float4*>(Wt + (size_t)(c0 + c)*1024 + r0 + (r4 << 2)) = ov;
    }
  } else {                              // ---- k1: (bh, eg, tc) ----
    int kid = bid - 512;
    int bh = kid & 15;  int eg = (kid >> 4) & 15;  int tc = kid >> 8;
    int b = bh >> 3, h = bh & 7;
    float4* QP = reinterpret_cast<float4*>(smem);        // 1024, XOR16 swizzle
    float4* Ks = QP + 1024;                              // 256 (this tc's t's)
    const float* qb  = q + (size_t)b*524288 + h*64 + eg*4;
    const float* kbp = k + (size_t)b*524288 + h*64 + eg*4;
    for (int r = tid; r < 1024; r += 256)
      QP[qsw(r)] = *reinterpret_cast<const float4*>(qb + (size_t)r*512);
    Ks[tid] = *reinterpret_cast<const float4*>(kbp + (size_t)((tc << 8) + tid)*512);
    __syncthreads();
    int lane = tid & 63;
    // per-lane Ks cache: lane l holds t-local rows 4l..4l+3 (one-time LDS reads)
    float4 Kr0 = Ks[(lane << 2) + 0], Kr1 = Ks[(lane << 2) + 1];
    float4 Kr2 = Ks[(lane << 2) + 2], Kr3 = Ks[(lane << 2) + 3];
    int tau0 = tid << 2;                // 4 taus per thread
    int tt0 = tc << 8;
    float4 acc[4];
    #pragma unroll
    for (int i = 0; i < 4; ++i) acc[i] = make_float4(0,0,0,0);
    // window Q[t+tau0 .. t+tau0+7] in A0..A3,B0..B3 (depth-5 pipeline)
    int wb = tt0 + tau0;
    float4 A0 = QP[qsw((wb    ) & 1023)], A1 = QP[qsw((wb + 1) & 1023)];
    float4 A2 = QP[qsw((wb + 2) & 1023)], A3 = QP[qsw((wb + 3) & 1023)];
    float4 B0 = QP[qsw((wb + 4) & 1023)], B1 = QP[qsw((wb + 5) & 1023)];
    float4 B2 = QP[qsw((wb + 6) & 1023)], B3 = QP[qsw((wb + 7) & 1023)];
    for (int t = 0; t < 256; t += 8) {
      int S = wb + t + 8;               // window refill base
      int lb_ = t >> 2;                 // uniform readlane base for this group
      float4 kv;
      // p=0 (t-local t+0): Ks at lane lb_, reg 0
      kv = rdl4(Kr0, lb_);
      fma4(acc[0],A0,kv); fma4(acc[1],A1,kv); fma4(acc[2],A2,kv); fma4(acc[3],A3,kv);
      A0 = QP[qsw((S+0) & 1023)];
      // p=1
      kv = rdl4(Kr1, lb_);
      fma4(acc[0],A1,kv); fma4(acc[1],A2,kv); fma4(acc[2],A3,kv); fma4(acc[3],B0,kv);
      A1 = QP[qsw((S+1) & 1023)];
      // p=2
      kv = rdl4(Kr2, lb_);
      fma4(acc[0],A2,kv); fma4(acc[1],A3,kv); fma4(acc[2],B0,kv); fma4(acc[3],B1,kv);
      A2 = QP[qsw((S+2) & 1023)];
      // p=3
      kv = rdl4(Kr3, lb_);
      fma4(acc[0],A3,kv); fma4(acc[1],B0,kv); fma4(acc[2],B1,kv); fma4(acc[3],B2,kv);
      A3 = QP[qsw((S+3) & 1023)];
      // p=4
      kv = rdl4(Kr0, lb_ + 1);
      fma4(acc[0],B0,kv); fma4(acc[1],B1,kv); fma4(acc[2],B2,kv); fma4(acc[3],B3,kv);
      B0 = QP[qsw((S+4) & 1023)];
      // p=5
      kv = rdl4(Kr1, lb_ + 1);
      fma4(acc[0],B1,kv); fma4(acc[1],B2,kv); fma4(acc[2],B3,kv); fma4(acc[3],A0,kv);
      B1 = QP[qsw((S+5) & 1023)];
      // p=6
      kv = rdl4(Kr2, lb_ + 1);
      fma4(acc[0],B2,kv); fma4(acc[1],B3,kv); fma4(acc[2],A0,kv); fma4(acc[3],A1,kv);
      B2 = QP[qsw((S+6) & 1023)];
      // p=7
      kv = rdl4(Kr3, lb_ + 1);
      fma4(acc[0],B3,kv); fma4(acc[1],A0,kv); fma4(acc[2],A1,kv); fma4(acc[3],A2,kv);
      B3 = QP[qsw((S+7) & 1023)];
    }
    // raw 4e partials for this tc chunk: thread owns taus tau0..tau0+3
    float4* op = reinterpret_cast<float4*>(acp)
               + (((size_t)((bh*16 + eg)*4 + tc)) << 10) + tau0;
    #pragma unroll
    for (int i = 0; i < 4; ++i) op[i] = acc[i];
  }
}

// ---------------- D2a: amp / tf-norm reduction, 512 blocks x 256 thr ----------------
__global__ __launch_bounds__(256) void d2a_amp(
    const float* __restrict__ acp, const float* __restrict__ tfq,
    float* __restrict__ amp, float* __restrict__ ampTF) {
  __shared__ float red[256];
  int bid = blockIdx.x;
  int tid = threadIdx.x;
  int lane = tid & 63, g = tid >> 6;     // 4 e-groups / 4 row-quarters
  if (bid < 256) {                        // ---- t: tc-combine + square + e-sum ----
    int bh = bid >> 4, tg = bid & 15;
    int tau = (tg << 6) + lane;
    const float4* A = reinterpret_cast<const float4*>(acp);
    float s = 0.f;
    #pragma unroll
    for (int eg4 = 0; eg4 < 4; ++eg4) {
      int eg = (g << 2) + eg4;
      const float4* E = A + (((size_t)(bh*16 + eg)) << 12);
      float4 c0 = E[tau], c1 = E[1024+tau], c2 = E[2048+tau], c3 = E[3072+tau];
      float x = c0.x+c1.x+c2.x+c3.x;
      float y = c0.y+c1.y+c2.y+c3.y;
      float z = c0.z+c1.z+c2.z+c3.z;
      float w = c0.w+c1.w+c2.w+c3.w;
      s += x*x + y*y + z*z + w*w;
    }
    red[tid] = s;
    __syncthreads();
    if (g == 0)
      amp[bh*1024 + tau] = red[lane] + red[64+lane] + red[128+lane] + red[192+lane];
  } else {                                // ---- tf: row norms ----
    int wid = bid - 256;
    int bh = wid >> 4, lg = wid & 15;
    int b = bh >> 3, h = bh & 7;
    int l = (lg << 6) + lane;
    const float4* p = reinterpret_cast<const float4*>(
        tfq + (((size_t)(b*1024 + l)*8 + h) << 6)) + (g << 2);
    float s = 0.f;
    #pragma unroll
    for (int i = 0; i < 4; ++i) {
      float4 vv = p[i];
      s += vv.x*vv.x + vv.y*vv.y + vv.z*vv.z + vv.w*vv.w;
    }
    red[tid] = s;
    __syncthreads();
    if (g == 0)
      ampTF[bh*1024 + l] = red[lane] + red[64+lane] + red[128+lane] + red[192+lane];
  }
}

// ---------------- D2b: top-35 both branches, 32 blocks x 1 wave ----------------
__global__ __launch_bounds__(64) void d2b_topk(
    const float* __restrict__ amp, const float* __restrict__ ampTF,
    int* __restrict__ St, int* __restrict__ Stf) {
  __shared__ float vals[1024];
  int bid = blockIdx.x;
  int tid = threadIdx.x;
  bool isT = bid < 16;
  int bh = isT ? bid : bid - 16;
  const float* src = (isT ? amp : ampTF) + bh*1024;
  #pragma unroll
  for (int s = 0; s < 16; ++s) vals[(s << 6) + tid] = src[(s << 6) + tid];
  __syncthreads();
  wave_top35(vals, (isT ? St : Stf) + bh*40);
}

// ---------------- D3: k4 (blocks 0..511) | kb (512..1663) ----------------
__global__ __launch_bounds__(256) void d3_mix(
    const float* __restrict__ q, const float* __restrict__ k,
    const float* __restrict__ tfq,
    const float* __restrict__ Wt, const float* __restrict__ bias,
    const float* __restrict__ values,
    const int* __restrict__ St, const int* __restrict__ Stf,
    float* __restrict__ WVp, float* __restrict__ P) {
  __shared__ float4 smbuf[1712];        // 27392 B (k4); kb uses first 8 KB
  float* f = reinterpret_cast<float*>(smbuf);
  int bid = blockIdx.x;
  int tid = threadIdx.x;
  if (bid >= 512) {                     // ---- kb: WVp partial, LDS-staged rows ----
    int kbid = bid - 512;
    int jq = kbid / 64;                 // 0..17
    int rem = kbid - jq*64;
    int bh = rem >> 2, mc = rem & 3;
    int b = bh >> 3, h = bh & 7;
    int j0 = jq << 2;
    int mbase = mc << 8;
    float* rows = f + 1024;             // 4 rows x 256 m-chunk = 4 KB
    #pragma unroll
    for (int x = 0; x < 4; ++x) {
      int j = j0 + x;
      const float* pj;
      if (j < NTOP)      pj = Wt + (size_t)St [bh*40 + j]*1024;
      else if (j < NJ)   pj = Wt + (size_t)(1024 + Stf[bh*40 + j-NTOP])*1024;
      else if (j == NJ)  pj = bias;
      else               pj = Wt;       // j==71: garbage, zeroed in epilogue
      rows[(x << 8) + tid] = pj[mbase + tid];
    }
    __syncthreads();
    int d = tid & 63, mp = tid >> 6;    // wave mp owns contiguous m-chunk of 64
    float a0=0.f, a1=0.f, a2=0.f, a3=0.f;
    const float4* r4 = reinterpret_cast<const float4*>(rows);
    const float* vbase = values
        + (((size_t)(b*1024 + mbase + (mp << 6))*8 + h) << 6) + d;
    #pragma unroll 4
    for (int i4 = 0; i4 < 16; ++i4) {
      float4 w0 = r4[       (mp << 4) + i4];
      float4 w1 = r4[ 64  + (mp << 4) + i4];
      float4 w2 = r4[128  + (mp << 4) + i4];
      float4 w3 = r4[192  + (mp << 4) + i4];
      float v0 = vbase[(size_t)((i4 << 2) + 0)*512];
      float v1 = vbase[(size_t)((i4 << 2) + 1)*512];
      float v2 = vbase[(size_t)((i4 << 2) + 2)*512];
      float v3 = vbase[(size_t)((i4 << 2) + 3)*512];
      a0 = fmaf(w0.x,v0,a0); a0 = fmaf(w0.y,v1,a0);
      a0 = fmaf(w0.z,v2,a0); a0 = fmaf(w0.w,v3,a0);
      a1 = fmaf(w1.x,v0,a1); a1 = fmaf(w1.y,v1,a1);
      a1 = fmaf(w1.z,v2,a1); a1 = fmaf(w1.w,v3,a1);
      a2 = fmaf(w2.x,v0,a2); a2 = fmaf(w2.y,v1,a2);
      a2 = fmaf(w2.z,v2,a2); a2 = fmaf(w2.w,v3,a2);
      a3 = fmaf(w3.x,v0,a3); a3 = fmaf(w3.y,v1,a3);
      a3 = fmaf(w3.z,v2,a3); a3 = fmaf(w3.w,v3,a3);
    }
    float4* red = smbuf;                // f[0..1024), disjoint from rows
    red[tid] = make_float4(a0, a1, a2, a3);
    __syncthreads();
    int jj = tid >> 6, dd = tid & 63;
    float4 r0 = red[dd], r1 = red[64+dd], r2 = red[128+dd], r3 = red[192+dd];
    float s;
    if (jj == 0)      s = r0.x + r1.x + r2.x + r3.x;
    else if (jj == 1) s = r0.y + r1.y + r2.y + r3.y;
    else if (jj == 2) s = r0.z + r1.z + r2.z + r3.z;
    else              s = r0.w + r1.w + r2.w + r3.w;
    if (j0 + jj > NJ) s = 0.f;
    WVp[(size_t)mc*73728 + ((size_t)bh*72 + j0 + jj)*64 + dd] = s;
  } else {                              // ---- k4 ----
    int gid = bid;
    int bh = gid >> 5;  int m0 = (gid & 31) << 5;
    int b = bh >> 3, h = bh & 7;
    float* qs   = f;                    // 35*64
    float* ts   = f + 2240;
    float* sc   = f + 4480;             // 32*73
    float* invs = f + 6816;             // 32
    for (int i = tid; i < NTOP*64; i += 256) {
      int j = i >> 6, e = i & 63;
      qs[i] = q  [(((size_t)(b*1024 + St [bh*40 + j])*8 + h) << 6) + e];
      ts[i] = tfq[(((size_t)(b*1024 + Stf[bh*40 + j])*8 + h) << 6) + e];
    }
    __syncthreads();
    int mi = tid & 31, g = tid >> 5;
    int br = g >> 2, g4 = g & 3;
    int m = m0 + mi;
    const float* src = br ? tfq : k;
    float4 kr[16];
    const float4* p = reinterpret_cast<const float4*>(
        src + (((size_t)(b*1024 + m)*8 + h) << 6));
    #pragma unroll
    for (int i = 0; i < 16; ++i) kr[i] = p[i];
    const float4* fs4 = reinterpret_cast<const float4*>(br ? ts : qs);
    int sb = br ? NTOP : 0;
    for (int j = g4; j < NTOP; j += 4) {
      float s = 0.f;
      #pragma unroll
      for (int e4 = 0; e4 < 16; ++e4) {
        float4 qv = fs4[j*16 + e4];
        s += qv.x*kr[e4].x + qv.y*kr[e4].y + qv.z*kr[e4].z + qv.w*kr[e4].w;
      }
      sc[mi*73 + sb + j] = s * 0.125f;
    }
    __syncthreads();
    if (tid < 32) {
      float mx = -1e30f;
      for (int j = 0; j < NJ; ++j) mx = fmaxf(mx, sc[tid*73 + j]);
      float sum = 0.f;
      for (int j = 0; j < NJ; ++j) {
        float e = __expf(sc[tid*73 + j] - mx);
        sc[tid*73 + j] = e; sum += e;
      }
      invs[tid] = 1.0f / sum;
    }
    __syncthreads();
    float* Pb = P + ((size_t)bh*1024 + m0)*72;
    for (int i = tid; i < 32*72; i += 256) {
      int mm = i / 72, j = i - mm*72;
      Pb[i] = (j < NJ) ? sc[mm*73 + j] * invs[mm] : 0.f;
    }
  }
}

// ---------------- D4: k6 per-bh, 512 thr, LDS Wv + transposed P chunk ----------------
__global__ __launch_bounds__(512) void k6_out(
    const float* __restrict__ P, const float* __restrict__ WVp,
    float* __restrict__ out) {
  __shared__ float wv[72*64];           // 18432 B
  __shared__ float Pl[72*68];           // 19584 B
  int bh = blockIdx.x, lc = blockIdx.y;
  int l0 = lc << 6;
  int b = bh >> 3, h = bh & 7;
  int tid = threadIdx.x;
  {
    const float* W0 = WVp + (size_t)bh*4608;
    for (int i = tid; i < 4608; i += 512)
      wv[i] = W0[i] + W0[73728 + i] + W0[147456 + i] + W0[221184 + i];
  }
  {
    const float* Pg = P + ((size_t)bh*1024 + l0)*72;
    for (int i = tid; i < 4608; i += 512) {
      int l = i / 72, j = i - l*72;
      Pl[j*68 + l] = Pg[i];
    }
  }
  __syncthreads();
  int d = tid & 63, lg = tid >> 6;      // 8 l-groups of 8
  int lb = lg << 3;
  float acc[8];
  float base = wv[NJ*64 + d];
  #pragma unroll
  for (int i = 0; i < 8; ++i) acc[i] = base;
  for (int j = 0; j < NJ; ++j) {
    float wvj = wv[j*64 + d];
    const float4* pr = reinterpret_cast<const float4*>(Pl + j*68 + lb);
    float4 p0 = pr[0], p1 = pr[1];
    acc[0] = fmaf(p0.x, wvj, acc[0]); acc[1] = fmaf(p0.y, wvj, acc[1]);
    acc[2] = fmaf(p0.z, wvj, acc[2]); acc[3] = fmaf(p0.w, wvj, acc[3]);
    acc[4] = fmaf(p1.x, wvj, acc[4]); acc[5] = fmaf(p1.y, wvj, acc[5]);
    acc[6] = fmaf(p1.z, wvj, acc[6]); acc[7] = fmaf(p1.w, wvj, acc[7]);
  }
  #pragma unroll
  for (int i = 0; i < 8; ++i) {
    int l = l0 + lb + i;
    out[(((size_t)(b*1024 + l)*8 + h) << 6) + d] = acc[i];
  }
}

extern "C" void kernel_launch(void* const* d_in, const int* in_sizes, int n_in,
                              void* d_out, int out_size, void* d_ws, size_t ws_size,
                              hipStream_t stream) {
  const float* tfq  = (const float*)d_in[0];
  const float* q    = (const float*)d_in[1];
  const float* k    = (const float*)d_in[2];
  const float* v    = (const float*)d_in[3];
  const float* tw   = (const float*)d_in[5];
  const float* tb   = (const float*)d_in[6];
  float* out = (float*)d_out;

  char* ws = (char*)d_ws;
  float* acp  = (float*)(ws);                       // 16,777,216
  int*   St   = (int*)  (ws + 16777216);            // 4 KB
  int*   Stf  = (int*)  (ws + 16781312);            // 4 KB
  float* Wt   = (float*)(ws + 16785408);            // 8,388,608
  float* P    = (float*)(ws + 25174016);            // 4,718,592
  float* WVp  = (float*)(ws + 29892608);            // 1,179,648
  float* amp  = (float*)(ws + 31072256);            // 64 KB
  float* ampTF= (float*)(ws + 31137792);            // 64 KB

  d1_prep<<<1536, 256, 0, stream>>>(q, k, tw, Wt, acp);
  d2a_amp<<<512, 256, 0, stream>>>(acp, tfq, amp, ampTF);
  d2b_topk<<<32, 64, 0, stream>>>(amp, ampTF, St, Stf);
  d3_mix <<<1664, 256, 0, stream>>>(q, k, tfq, Wt, tb, v, St, Stf, WVp, P);
  k6_out <<<dim3(16, 16), 512, 0, stream>>>(P, WVp, out);
}

// Round 13
// 176.189 us; speedup vs baseline: 2.4526x; 1.0533x over previous
//
#include <hip/hip_runtime.h>

// MixSelfAttention (B=2, L=1024, H=8, E=64), float32 in/out. 4 dispatches.
// r12 lesson: readlane-Ks regressed (VALU 37us > saved LDS 20us) -> reverted;
// k1 is at its LDS-pipe structural floor (~44us). This round removes one
// dispatch boundary (~11us, r9 evidence) by merging d2a+d2b back into the
// round-0 d2_topk (32 blocks x 1024 thr: per-bh reduction + in-block top35 --
// known-passing code, one top35 per bh so no r9 latency blowup).
//   D1 d1: kw tile-transpose W -> Wt (blocks 0..511, 65-pad, <=2-way banks)
//          | k1 circular-corr partials (512..1535), T=4 taus/thread, depth-5
//          A/B window pipeline, Ks broadcast, XOR16 QP -> acp[bh][eg][tc][tau][4e]
//   D2 d2: 32 blocks x 1024 thr; t: tc-combine+square+e-sum | tf: row norms
//          -> vals[1024] in LDS -> wave0 top-35 -> St / Stf
//   D3 d3: k4 scores+softmax -> P (0..511) | kb WVp partials (512..1663)
//   D4 k6: per-bh blocks, 512 thr; Wv=sum_mc WVp in LDS + transposed P

#define NTOP 35
#define NJ 70
#define LLMIN (-0x7FFFFFFFFFFFFFFFLL - 1)

static __device__ __forceinline__ void fma4(float4& a, float4 q, float4 k) {
  a.x = fmaf(q.x,k.x,a.x); a.y = fmaf(q.y,k.y,a.y);
  a.z = fmaf(q.z,k.z,a.z); a.w = fmaf(q.w,k.w,a.w);
}

// single-wave top-35 (lanes 0..63 call), vals[1024] ready, jax tie-break
static __device__ __forceinline__ void wave_top35(const float* vals, int* out) {
  int lane = threadIdx.x & 63;
  long long kreg[16];
  long long lmax = LLMIN;
  #pragma unroll
  for (int s = 0; s < 16; ++s) {
    int l = (s << 6) + lane;
    long long key = ((long long)(int)__float_as_uint(vals[l]) << 32)
                    | (unsigned int)(1023 - l);
    kreg[s] = key;
    lmax = key > lmax ? key : lmax;
  }
  for (int it = 0; it < NTOP; ++it) {
    long long g = lmax;
    #pragma unroll
    for (int off = 1; off < 64; off <<= 1) {
      long long o = __shfl_xor(g, off);
      g = o > g ? o : g;
    }
    if (lane == 0) out[it] = 1023 - (int)(g & 0xFFFFFFFFLL);
    if (lmax == g) {
      lmax = LLMIN;
      #pragma unroll
      for (int s = 0; s < 16; ++s) {
        if (kreg[s] == g) kreg[s] = LLMIN;
        lmax = kreg[s] > lmax ? kreg[s] : lmax;
      }
    }
  }
}

// XOR16 swizzle: conflict-free for stride-1 staging AND window reads
static __device__ __forceinline__ int qsw(int r) { return r ^ ((r >> 4) & 7); }

// ---------------- D1: kw (blocks 0..511) | k1 (512..1535), 256 thr ----------------
__global__ __launch_bounds__(256) void d1_prep(
    const float* __restrict__ q, const float* __restrict__ k,
    const float* __restrict__ w,
    float* __restrict__ Wt, float* __restrict__ acp) {
  __shared__ float smem[5200];          // 20.8 KB: QP 1024 f4 + Ks 256 f4 / kw tile
  int bid = blockIdx.x;
  int tid = threadIdx.x;
  if (bid < 512) {                      // ---- kw: f4-load 65-pad transpose ----
    int c0 = (bid & 31) << 6, r0 = (bid >> 5) << 6;
    float* tile = smem;                 // 64 x 65 floats = 4160 < 5200
    #pragma unroll
    for (int s = 0; s < 4; ++s) {
      int idx = (s << 8) + tid;         // 0..1023 f4 elems
      int r = idx >> 4, c4 = idx & 15;
      float4 vv = *reinterpret_cast<const float4*>(
          w + (size_t)(r0 + r)*2048 + c0 + (c4 << 2));
      float* tp = tile + r*65 + (c4 << 2);
      tp[0] = vv.x; tp[1] = vv.y; tp[2] = vv.z; tp[3] = vv.w;
    }
    __syncthreads();
    #pragma unroll
    for (int s = 0; s < 4; ++s) {
      int idx = (s << 8) + tid;
      int c = idx >> 4, r4 = idx & 15;
      float4 ov;
      ov.x = tile[(r4*4 + 0)*65 + c];
      ov.y = tile[(r4*4 + 1)*65 + c];
      ov.z = tile[(r4*4 + 2)*65 + c];
      ov.w = tile[(r4*4 + 3)*65 + c];
      *reinterpret_cast<float4*>(Wt + (size_t)(c0 + c)*1024 + r0 + (r4 << 2)) = ov;
    }
  } else {                              // ---- k1: (bh, eg, tc) ----
    int kid = bid - 512;
    int bh = kid & 15;  int eg = (kid >> 4) & 15;  int tc = kid >> 8;
    int b = bh >> 3, h = bh & 7;
    float4* QP = reinterpret_cast<float4*>(smem);        // 1024, XOR16 swizzle
    float4* Ks = QP + 1024;                              // 256 (this tc's t's)
    const float* qb  = q + (size_t)b*524288 + h*64 + eg*4;
    const float* kbp = k + (size_t)b*524288 + h*64 + eg*4;
    for (int r = tid; r < 1024; r += 256)
      QP[qsw(r)] = *reinterpret_cast<const float4*>(qb + (size_t)r*512);
    Ks[tid] = *reinterpret_cast<const float4*>(kbp + (size_t)((tc << 8) + tid)*512);
    __syncthreads();
    int tau0 = tid << 2;                // 4 taus per thread: tau0..tau0+3
    int tt0 = tc << 8;                  // absolute t base of this tc
    float4 acc[4];
    #pragma unroll
    for (int i = 0; i < 4; ++i) acc[i] = make_float4(0,0,0,0);
    // window Q[t+tau0 .. t+tau0+7] in A0..A3,B0..B3 (depth-5 pipeline)
    int wb = tt0 + tau0;
    float4 A0 = QP[qsw((wb    ) & 1023)], A1 = QP[qsw((wb + 1) & 1023)];
    float4 A2 = QP[qsw((wb + 2) & 1023)], A3 = QP[qsw((wb + 3) & 1023)];
    float4 B0 = QP[qsw((wb + 4) & 1023)], B1 = QP[qsw((wb + 5) & 1023)];
    float4 B2 = QP[qsw((wb + 6) & 1023)], B3 = QP[qsw((wb + 7) & 1023)];
    for (int t = 0; t < 256; t += 8) {
      int S = wb + t + 8;               // refill base for this group
      float4 kv;
      kv = Ks[t+0];
      fma4(acc[0],A0,kv); fma4(acc[1],A1,kv); fma4(acc[2],A2,kv); fma4(acc[3],A3,kv);
      A0 = QP[qsw((S+0) & 1023)];
      kv = Ks[t+1];
      fma4(acc[0],A1,kv); fma4(acc[1],A2,kv); fma4(acc[2],A3,kv); fma4(acc[3],B0,kv);
      A1 = QP[qsw((S+1) & 1023)];
      kv = Ks[t+2];
      fma4(acc[0],A2,kv); fma4(acc[1],A3,kv); fma4(acc[2],B0,kv); fma4(acc[3],B1,kv);
      A2 = QP[qsw((S+2) & 1023)];
      kv = Ks[t+3];
      fma4(acc[0],A3,kv); fma4(acc[1],B0,kv); fma4(acc[2],B1,kv); fma4(acc[3],B2,kv);
      A3 = QP[qsw((S+3) & 1023)];
      kv = Ks[t+4];
      fma4(acc[0],B0,kv); fma4(acc[1],B1,kv); fma4(acc[2],B2,kv); fma4(acc[3],B3,kv);
      B0 = QP[qsw((S+4) & 1023)];
      kv = Ks[t+5];
      fma4(acc[0],B1,kv); fma4(acc[1],B2,kv); fma4(acc[2],B3,kv); fma4(acc[3],A0,kv);
      B1 = QP[qsw((S+5) & 1023)];
      kv = Ks[t+6];
      fma4(acc[0],B2,kv); fma4(acc[1],B3,kv); fma4(acc[2],A0,kv); fma4(acc[3],A1,kv);
      B2 = QP[qsw((S+6) & 1023)];
      kv = Ks[t+7];
      fma4(acc[0],B3,kv); fma4(acc[1],A0,kv); fma4(acc[2],A1,kv); fma4(acc[3],A2,kv);
      B3 = QP[qsw((S+7) & 1023)];
    }
    // raw 4e partials for this tc chunk: thread owns taus tau0..tau0+3
    float4* op = reinterpret_cast<float4*>(acp)
               + (((size_t)((bh*16 + eg)*4 + tc)) << 10) + tau0;
    #pragma unroll
    for (int i = 0; i < 4; ++i) op[i] = acc[i];
  }
}

// ---------------- D2: per-bh reduction + top-35, 32 blocks x 1024 thr ----------------
__global__ __launch_bounds__(1024) void d2_topk(
    const float* __restrict__ acp, const float* __restrict__ tfq,
    int* __restrict__ St, int* __restrict__ Stf) {
  __shared__ float vals[1024];
  int bid = blockIdx.x;
  int tid = threadIdx.x;
  bool isT = bid < 16;
  int bh = isT ? bid : bid - 16;
  if (isT) {                            // t: combine tc chunks, square, sum e
    int tau = tid;
    const float4* A = reinterpret_cast<const float4*>(acp);
    float s = 0.f;
    #pragma unroll
    for (int eg = 0; eg < 16; ++eg) {
      const float4* E = A + (((size_t)(bh*16 + eg)) << 12);
      float4 c0 = E[tau], c1 = E[1024+tau], c2 = E[2048+tau], c3 = E[3072+tau];
      float x = c0.x+c1.x+c2.x+c3.x;
      float y = c0.y+c1.y+c2.y+c3.y;
      float z = c0.z+c1.z+c2.z+c3.z;
      float w = c0.w+c1.w+c2.w+c3.w;
      s += x*x + y*y + z*z + w*w;
    }
    vals[tau] = s;
  } else {                              // tf: row norms
    int b = bh >> 3, h = bh & 7;
    const float4* p = reinterpret_cast<const float4*>(
        tfq + (((size_t)(b*1024 + tid)*8 + h) << 6));
    float s = 0.f;
    #pragma unroll
    for (int i = 0; i < 16; ++i) {
      float4 vv = p[i];
      s += vv.x*vv.x + vv.y*vv.y + vv.z*vv.z + vv.w*vv.w;
    }
    vals[tid] = s;
  }
  __syncthreads();
  if (tid < 64) wave_top35(vals, (isT ? St : Stf) + bh*40);
}

// ---------------- D3: k4 (blocks 0..511) | kb (512..1663) ----------------
__global__ __launch_bounds__(256) void d3_mix(
    const float* __restrict__ q, const float* __restrict__ k,
    const float* __restrict__ tfq,
    const float* __restrict__ Wt, const float* __restrict__ bias,
    const float* __restrict__ values,
    const int* __restrict__ St, const int* __restrict__ Stf,
    float* __restrict__ WVp, float* __restrict__ P) {
  __shared__ float4 smbuf[1712];        // 27392 B (k4); kb uses first 8 KB
  float* f = reinterpret_cast<float*>(smbuf);
  int bid = blockIdx.x;
  int tid = threadIdx.x;
  if (bid >= 512) {                     // ---- kb: WVp partial, LDS-staged rows ----
    int kbid = bid - 512;
    int jq = kbid / 64;                 // 0..17
    int rem = kbid - jq*64;
    int bh = rem >> 2, mc = rem & 3;
    int b = bh >> 3, h = bh & 7;
    int j0 = jq << 2;
    int mbase = mc << 8;
    float* rows = f + 1024;             // 4 rows x 256 m-chunk = 4 KB
    #pragma unroll
    for (int x = 0; x < 4; ++x) {
      int j = j0 + x;
      const float* pj;
      if (j < NTOP)      pj = Wt + (size_t)St [bh*40 + j]*1024;
      else if (j < NJ)   pj = Wt + (size_t)(1024 + Stf[bh*40 + j-NTOP])*1024;
      else if (j == NJ)  pj = bias;
      else               pj = Wt;       // j==71: garbage, zeroed in epilogue
      rows[(x << 8) + tid] = pj[mbase + tid];
    }
    __syncthreads();
    int d = tid & 63, mp = tid >> 6;    // wave mp owns contiguous m-chunk of 64
    float a0=0.f, a1=0.f, a2=0.f, a3=0.f;
    const float4* r4 = reinterpret_cast<const float4*>(rows);
    const float* vbase = values
        + (((size_t)(b*1024 + mbase + (mp << 6))*8 + h) << 6) + d;
    #pragma unroll 4
    for (int i4 = 0; i4 < 16; ++i4) {
      float4 w0 = r4[       (mp << 4) + i4];
      float4 w1 = r4[ 64  + (mp << 4) + i4];
      float4 w2 = r4[128  + (mp << 4) + i4];
      float4 w3 = r4[192  + (mp << 4) + i4];
      float v0 = vbase[(size_t)((i4 << 2) + 0)*512];
      float v1 = vbase[(size_t)((i4 << 2) + 1)*512];
      float v2 = vbase[(size_t)((i4 << 2) + 2)*512];
      float v3 = vbase[(size_t)((i4 << 2) + 3)*512];
      a0 = fmaf(w0.x,v0,a0); a0 = fmaf(w0.y,v1,a0);
      a0 = fmaf(w0.z,v2,a0); a0 = fmaf(w0.w,v3,a0);
      a1 = fmaf(w1.x,v0,a1); a1 = fmaf(w1.y,v1,a1);
      a1 = fmaf(w1.z,v2,a1); a1 = fmaf(w1.w,v3,a1);
      a2 = fmaf(w2.x,v0,a2); a2 = fmaf(w2.y,v1,a2);
      a2 = fmaf(w2.z,v2,a2); a2 = fmaf(w2.w,v3,a2);
      a3 = fmaf(w3.x,v0,a3); a3 = fmaf(w3.y,v1,a3);
      a3 = fmaf(w3.z,v2,a3); a3 = fmaf(w3.w,v3,a3);
    }
    float4* red = smbuf;                // f[0..1024), disjoint from rows
    red[tid] = make_float4(a0, a1, a2, a3);
    __syncthreads();
    int jj = tid >> 6, dd = tid & 63;
    float4 r0 = red[dd], r1 = red[64+dd], r2 = red[128+dd], r3 = red[192+dd];
    float s;
    if (jj == 0)      s = r0.x + r1.x + r2.x + r3.x;
    else if (jj == 1) s = r0.y + r1.y + r2.y + r3.y;
    else if (jj == 2) s = r0.z + r1.z + r2.z + r3.z;
    else              s = r0.w + r1.w + r2.w + r3.w;
    if (j0 + jj > NJ) s = 0.f;
    WVp[(size_t)mc*73728 + ((size_t)bh*72 + j0 + jj)*64 + dd] = s;
  } else {                              // ---- k4 ----
    int gid = bid;
    int bh = gid >> 5;  int m0 = (gid & 31) << 5;
    int b = bh >> 3, h = bh & 7;
    float* qs   = f;                    // 35*64
    float* ts   = f + 2240;
    float* sc   = f + 4480;             // 32*73
    float* invs = f + 6816;             // 32
    for (int i = tid; i < NTOP*64; i += 256) {
      int j = i >> 6, e = i & 63;
      qs[i] = q  [(((size_t)(b*1024 + St [bh*40 + j])*8 + h) << 6) + e];
      ts[i] = tfq[(((size_t)(b*1024 + Stf[bh*40 + j])*8 + h) << 6) + e];
    }
    __syncthreads();
    int mi = tid & 31, g = tid >> 5;
    int br = g >> 2, g4 = g & 3;
    int m = m0 + mi;
    const float* src = br ? tfq : k;
    float4 kr[16];
    const float4* p = reinterpret_cast<const float4*>(
        src + (((size_t)(b*1024 + m)*8 + h) << 6));
    #pragma unroll
    for (int i = 0; i < 16; ++i) kr[i] = p[i];
    const float4* fs4 = reinterpret_cast<const float4*>(br ? ts : qs);
    int sb = br ? NTOP : 0;
    for (int j = g4; j < NTOP; j += 4) {
      float s = 0.f;
      #pragma unroll
      for (int e4 = 0; e4 < 16; ++e4) {
        float4 qv = fs4[j*16 + e4];
        s += qv.x*kr[e4].x + qv.y*kr[e4].y + qv.z*kr[e4].z + qv.w*kr[e4].w;
      }
      sc[mi*73 + sb + j] = s * 0.125f;
    }
    __syncthreads();
    if (tid < 32) {
      float mx = -1e30f;
      for (int j = 0; j < NJ; ++j) mx = fmaxf(mx, sc[tid*73 + j]);
      float sum = 0.f;
      for (int j = 0; j < NJ; ++j) {
        float e = __expf(sc[tid*73 + j] - mx);
        sc[tid*73 + j] = e; sum += e;
      }
      invs[tid] = 1.0f / sum;
    }
    __syncthreads();
    float* Pb = P + ((size_t)bh*1024 + m0)*72;
    for (int i = tid; i < 32*72; i += 256) {
      int mm = i / 72, j = i - mm*72;
      Pb[i] = (j < NJ) ? sc[mm*73 + j] * invs[mm] : 0.f;
    }
  }
}

// ---------------- D4: k6 per-bh, 512 thr, LDS Wv + transposed P chunk ----------------
__global__ __launch_bounds__(512) void k6_out(
    const float* __restrict__ P, const float* __restrict__ WVp,
    float* __restrict__ out) {
  __shared__ float wv[72*64];           // 18432 B
  __shared__ float Pl[72*68];           // 19584 B
  int bh = blockIdx.x, lc = blockIdx.y;
  int l0 = lc << 6;
  int b = bh >> 3, h = bh & 7;
  int tid = threadIdx.x;
  {
    const float* W0 = WVp + (size_t)bh*4608;
    for (int i = tid; i < 4608; i += 512)
      wv[i] = W0[i] + W0[73728 + i] + W0[147456 + i] + W0[221184 + i];
  }
  {
    const float* Pg = P + ((size_t)bh*1024 + l0)*72;
    for (int i = tid; i < 4608; i += 512) {
      int l = i / 72, j = i - l*72;
      Pl[j*68 + l] = Pg[i];
    }
  }
  __syncthreads();
  int d = tid & 63, lg = tid >> 6;      // 8 l-groups of 8
  int lb = lg << 3;
  float acc[8];
  float base = wv[NJ*64 + d];
  #pragma unroll
  for (int i = 0; i < 8; ++i) acc[i] = base;
  for (int j = 0; j < NJ; ++j) {
    float wvj = wv[j*64 + d];
    const float4* pr = reinterpret_cast<const float4*>(Pl + j*68 + lb);
    float4 p0 = pr[0], p1 = pr[1];
    acc[0] = fmaf(p0.x, wvj, acc[0]); acc[1] = fmaf(p0.y, wvj, acc[1]);
    acc[2] = fmaf(p0.z, wvj, acc[2]); acc[3] = fmaf(p0.w, wvj, acc[3]);
    acc[4] = fmaf(p1.x, wvj, acc[4]); acc[5] = fmaf(p1.y, wvj, acc[5]);
    acc[6] = fmaf(p1.z, wvj, acc[6]); acc[7] = fmaf(p1.w, wvj, acc[7]);
  }
  #pragma unroll
  for (int i = 0; i < 8; ++i) {
    int l = l0 + lb + i;
    out[(((size_t)(b*1024 + l)*8 + h) << 6) + d] = acc[i];
  }
}

extern "C" void kernel_launch(void* const* d_in, const int* in_sizes, int n_in,
                              void* d_out, int out_size, void* d_ws, size_t ws_size,
                              hipStream_t stream) {
  const float* tfq  = (const float*)d_in[0];
  const float* q    = (const float*)d_in[1];
  const float* k    = (const float*)d_in[2];
  const float* v    = (const float*)d_in[3];
  const float* tw   = (const float*)d_in[5];
  const float* tb   = (const float*)d_in[6];
  float* out = (float*)d_out;

  char* ws = (char*)d_ws;
  float* acp  = (float*)(ws);                       // 16,777,216
  int*   St   = (int*)  (ws + 16777216);            // 4 KB
  int*   Stf  = (int*)  (ws + 16781312);            // 4 KB
  float* Wt   = (float*)(ws + 16785408);            // 8,388,608
  float* P    = (float*)(ws + 25174016);            // 4,718,592
  float* WVp  = (float*)(ws + 29892608);            // 1,179,648

  d1_prep<<<1536, 256, 0, stream>>>(q, k, tw, Wt, acp);
  d2_topk<<<32, 1024, 0, stream>>>(acp, tfq, St, Stf);
  d3_mix <<<1664, 256, 0, stream>>>(q, k, tfq, Wt, tb, v, St, Stf, WVp, P);
  k6_out <<<dim3(16, 16), 512, 0, stream>>>(P, WVp, out);
}